// Round 5
// baseline (219.881 us; speedup 1.0000x reference)
//
#include <hip/hip_runtime.h>
#include <stdint.h>

#define IN_F 512
#define OUT_F 512
#define NROWS 8192
#define NSLOT 12                 // 11 spline slots + 1 base(x) slot per in-feature
#define KTOT (IN_F * NSLOT)      // 6144
#define K16S (KTOT / 16)         // 384 k16-steps
#define MTILES (NROWS / 32)      // 256 A row-tiles
#define SW_ROW (IN_F * 11)       // 5632 floats per output row of spline_weight
#define KC_PAD 776               // prep kcol row stride (ushorts)

typedef __bf16 bf16x8 __attribute__((ext_vector_type(8)));
typedef float f32x16 __attribute__((ext_vector_type(16)));

// Frag-linear operand buffers (1 chunk = 64 lanes x 16B = one 32x16 MFMA frag).
// B chunk (ntg*384 + k16): lane l -> B[k16*16+(l>>5)*8+j][ntg*32 + (l&31)]
// A chunk (mtg*384 + k16): lane l -> A[mtg*32 + (l&31)][k16*16+(l>>5)*8+j]
// (+1 chunk pad: unroll-4 loop may touch one chunk past the end harmlessly)
__device__ ushort g_Wb[(K16S * 16 + 1) * 512];       //  6.3 MB
__device__ ushort g_A [(MTILES * K16S + 1) * 512];   // 100.7 MB

__device__ __forceinline__ ushort f2bf(float f) {
    uint32_t u = __builtin_bit_cast(uint32_t, f);
    u += 0x7FFFu + ((u >> 16) & 1u);          // RNE
    return (ushort)(u >> 16);
}

// ---- weight prep: 16 ntile x 8 kgroup blocks; coalesced in AND out ---------
__global__ __launch_bounds__(256) void prep_weights(const float* __restrict__ bw,
                                                    const float* __restrict__ sw) {
    __shared__ __align__(16) ushort kcol[32 * KC_PAD];    // 48.5 KB
    const int t  = threadIdx.x;
    const int nt = blockIdx.x & 15;           // outs [nt*32, +32)
    const int kg = blockIdx.x >> 4;           // feats [kg*64, +64) -> k16 [kg*48, +48)
    const int o0 = nt * 32;
    const int f0 = kg * 64;

    {
        const int o_l = t >> 3;               // 0..31
        const int tr  = t & 7;                // 8 threads per row
        const float* swr = sw + (size_t)(o0 + o_l) * SW_ROW + (size_t)f0 * 11;
        #pragma unroll
        for (int i = 0; i < 22; ++i) {
            int p4 = tr + i * 8;              // float4 idx 0..175
            float4 v = ((const float4*)swr)[p4];
            uint pos = (uint)p4 * 4;
            #pragma unroll
            for (int c = 0; c < 4; ++c) {
                uint pc = pos + c;            // 0..703
                uint fl = pc / 11u;
                uint j  = pc - fl * 11u;
                float val = (c == 0) ? v.x : (c == 1) ? v.y : (c == 2) ? v.z : v.w;
                kcol[o_l * KC_PAD + fl * NSLOT + j] = f2bf(val);
            }
        }
        #pragma unroll
        for (int i = 0; i < 8; ++i) {
            int fl = tr + i * 8;              // 0..63
            kcol[o_l * KC_PAD + fl * NSLOT + 11] =
                f2bf(bw[(size_t)(o0 + o_l) * IN_F + f0 + fl]);
        }
    }
    __syncthreads();

    {
        const int ol = t & 31;
        const int ph = t >> 5;                // 0..7
        #pragma unroll
        for (int i = 0; i < 12; ++i) {
            int idx  = ph + i * 8;            // 0..95
            int k16l = idx >> 1;
            int half = idx & 1;
            uint4 val = *(const uint4*)&kcol[ol * KC_PAD + k16l * 16 + half * 8];
            ((uint4*)g_Wb)[((size_t)nt * K16S + kg * 48 + k16l) * 64 + half * 32 + ol] = val;
        }
    }
}

// ---- basis eval: 12 packed slot-pair dwords for one x (slot 11 = raw x) ----
__device__ __forceinline__ void eval12(float xx, uint p[6]) {
    float wpos = (xx + 1.0f) * 7.0f;
    float fi = floorf(wpos);
    int   i  = (int)fi;
    float u  = wpos - fi;
    bool inr = (xx >= -1.0f) && (xx < 1.0f);
    int   q  = i - 3;
    float um = 1.0f - u;
    float uu = u * u, u3 = uu * u;
    const float C6 = 1.0f / 6.0f;
    float s0 = (inr && q >= 0) ? C6 : 0.0f;
    float s1 = (inr && q >= -1 && q <= 9) ? C6 : 0.0f;
    float s2 = (inr && q >= -2 && q <= 8) ? C6 : 0.0f;
    float s3 = (inr && q <= 7) ? C6 : 0.0f;
    uint b0 = f2bf(um * um * um * s0);
    uint b1 = f2bf((3.0f * u3 - 6.0f * uu + 4.0f) * s1);
    uint b2 = f2bf((-3.0f * u3 + 3.0f * uu + 3.0f * u + 1.0f) * s2);
    uint b3 = f2bf(u3 * s3);
    int r  = q & 1;
    int e0 = q & ~1;
    uint P0 = r ? (b0 << 16)        : (b0 | (b1 << 16));
    uint P1 = r ? (b1 | (b2 << 16)) : (b2 | (b3 << 16));
    uint P2 = r ? b3                : 0u;
    #pragma unroll
    for (int pi = 0; pi < 6; ++pi) {
        int d = 2 * pi - e0;
        p[pi] = (d == 0) ? P0 : (d == 2) ? P1 : (d == 4) ? P2 : 0u;
    }
    p[5] = (p[5] & 0xFFFFu) | ((uint)f2bf(xx) << 16);   // slot 11 = raw x
}

// ---- basis_eval: x -> g_A in MFMA A-frag-linear layout ---------------------
// block: mtile (32 rows) x 96 k16; wave w: 24 consecutive k16.
__global__ __launch_bounds__(256, 4) void basis_eval(const float* __restrict__ x) {
    const int t    = threadIdx.x;
    const int lane = t & 63;
    const int w    = t >> 6;
    const int r31  = lane & 31;
    const int half = lane >> 5;

    const int mt = blockIdx.x & 255;          // 0..255
    const int kq = blockIdx.x >> 8;           // 0..3
    const int row = mt * 32 + r31;
    const float* xr = x + (size_t)row * IN_F;
    uint4* Adst = (uint4*)g_A + ((size_t)mt * K16S) * 64 + lane;

    const int kbase = kq * 96 + w * 24;
    #pragma unroll 2
    for (int i = 0; i < 24; ++i) {
        const int k16 = kbase + i;
        const int s0  = k16 * 16 + half * 8;  // first of this lane's 8 slots
        const int f   = s0 / NSLOT;
        const int j0  = s0 - f * NSLOT;       // 0, 4, or 8
        const int fb  = (j0 == 8) ? (f + 1) : f;   // clamp: only used when j0==8
        float xa = xr[f];
        float xb = xr[fb];
        uint pa[6], pb[6];
        eval12(xa, pa);
        eval12(xb, pb);
        uint4 o;
        o.x = (j0 == 0) ? pa[0] : (j0 == 4) ? pa[2] : pa[4];
        o.y = (j0 == 0) ? pa[1] : (j0 == 4) ? pa[3] : pa[5];
        o.z = (j0 == 0) ? pa[2] : (j0 == 4) ? pa[4] : pb[0];
        o.w = (j0 == 0) ? pa[3] : (j0 == 4) ? pa[5] : pb[1];
        Adst[(size_t)k16 * 64] = o;
    }
}

// ---- barrier-free GEMM: frag-linear A and B straight from global -----------
// grid 512: bx = mb*8 + nt*2 + kp  (XCD = bx%8 = nt*2+kp -> B slice 0.79MB/XCD)
__global__ __launch_bounds__(256, 2) void kan_gemm(float* __restrict__ out) {
    const int t    = threadIdx.x;
    const int lane = t & 63;
    const int wv   = t >> 6;          // 0..3
    const int wr   = wv >> 1;         // wave row 0..1
    const int wc   = wv & 1;          // wave col 0..1
    const int ln31 = lane & 31;
    const int half = lane >> 5;

    const int bx = blockIdx.x;
    const int kp = bx & 1;            // K half
    const int nt = (bx >> 1) & 3;     // 128-col group
    const int mb = bx >> 3;           // 128-row group 0..63

    const int mtg0 = mb * 4 + wr * 2;
    const int ntg0 = nt * 4 + wc * 2;
    const size_t MS = (size_t)K16S * 64;          // mtg/ntg stride in uint4

    const uint4* Ap = (const uint4*)g_A  + (size_t)mtg0 * MS + (size_t)(kp * 192) * 64 + lane;
    const uint4* Bp = (const uint4*)g_Wb + (size_t)ntg0 * MS + (size_t)(kp * 192) * 64 + lane;

    f32x16 acc[2][2] = {};

    #pragma unroll 4
    for (int k = 0; k < 192; ++k) {
        uint4 a0 = Ap[(size_t)k * 64];
        uint4 a1 = Ap[MS + (size_t)k * 64];
        uint4 b0 = Bp[(size_t)k * 64];
        uint4 b1 = Bp[MS + (size_t)k * 64];
        bf16x8 af0 = __builtin_bit_cast(bf16x8, a0);
        bf16x8 af1 = __builtin_bit_cast(bf16x8, a1);
        bf16x8 bf0 = __builtin_bit_cast(bf16x8, b0);
        bf16x8 bf1 = __builtin_bit_cast(bf16x8, b1);
        acc[0][0] = __builtin_amdgcn_mfma_f32_32x32x16_bf16(af0, bf0, acc[0][0], 0, 0, 0);
        acc[0][1] = __builtin_amdgcn_mfma_f32_32x32x16_bf16(af0, bf1, acc[0][1], 0, 0, 0);
        acc[1][0] = __builtin_amdgcn_mfma_f32_32x32x16_bf16(af1, bf0, acc[1][0], 0, 0, 0);
        acc[1][1] = __builtin_amdgcn_mfma_f32_32x32x16_bf16(af1, bf1, acc[1][1], 0, 0, 0);
    }

    // epilogue: C layout col=lane&31, row=(reg&3)+8*(reg>>2)+4*(lane>>5)
    #pragma unroll
    for (int mt = 0; mt < 2; ++mt) {
        #pragma unroll
        for (int ntt = 0; ntt < 2; ++ntt) {
            int rb = (mtg0 + mt) * 32 + 4 * half;
            int cc = (ntg0 + ntt) * 32 + ln31;
            #pragma unroll
            for (int reg = 0; reg < 16; ++reg) {
                int rr = rb + (reg & 3) + 8 * (reg >> 2);
                unsafeAtomicAdd(&out[(size_t)rr * OUT_F + cc], acc[mt][ntt][reg]);
            }
        }
    }
}

extern "C" void kernel_launch(void* const* d_in, const int* in_sizes, int n_in,
                              void* d_out, int out_size, void* d_ws, size_t ws_size,
                              hipStream_t stream) {
    const float* x  = (const float*)d_in[0];
    const float* bw = (const float*)d_in[1];
    const float* sw = (const float*)d_in[2];
    float* out = (float*)d_out;
    hipMemsetAsync(out, 0, (size_t)out_size * sizeof(float), stream);
    hipLaunchKernelGGL(prep_weights, dim3(128), dim3(256), 0, stream, bw, sw);
    hipLaunchKernelGGL(basis_eval, dim3(1024), dim3(256), 0, stream, x);
    hipLaunchKernelGGL(kan_gemm, dim3(512), dim3(256), 0, stream, out);
}

// Round 6
// 207.647 us; speedup vs baseline: 1.0589x; 1.0589x over previous
//
#include <hip/hip_runtime.h>
#include <stdint.h>

#define IN_F 512
#define OUT_F 512
#define NROWS 8192
#define NSLOT 12                 // 11 spline slots + 1 base(x) slot per in-feature
#define KTOT (IN_F * NSLOT)      // 6144
#define K16S (KTOT / 16)         // 384 k16-steps
#define SW_ROW (IN_F * 11)       // 5632 floats per output row of spline_weight
#define KC_PAD 776               // prep kcol row stride (ushorts)
#define NGROUP 128               // K processed in 128 groups of 4 features (48 slots)
#define AROW 56                  // staging row stride (ushorts): 28 words -> 4-way max

typedef __bf16 bf16x8 __attribute__((ext_vector_type(8)));
typedef float f32x16 __attribute__((ext_vector_type(16)));

// frag-linear B: uint4 index (ntg*384 + k16)*64 + lane -> 8 bf16 =
//   B[k16*16+(lane>>5)*8+j][ntg*32 + (lane&31)],  k = f*12 + j_slot
__device__ ushort g_Wb[(K16S * 16 + 1) * 512];   // 6.3 MB
__device__ float  g_xT[IN_F * NROWS];            // 16 MB transposed x

__device__ __forceinline__ ushort f2bf(float f) {
    uint32_t u = __builtin_bit_cast(uint32_t, f);
    u += 0x7FFFu + ((u >> 16) & 1u);          // RNE
    return (ushort)(u >> 16);
}

// ---- weight prep: 16 ntile x 8 kgroup blocks; coalesced in AND out ---------
__global__ __launch_bounds__(256) void prep_weights(const float* __restrict__ bw,
                                                    const float* __restrict__ sw) {
    __shared__ __align__(16) ushort kcol[32 * KC_PAD];    // 48.5 KB
    const int t  = threadIdx.x;
    const int nt = blockIdx.x & 15;           // outs [nt*32, +32)
    const int kg = blockIdx.x >> 4;           // feats [kg*64, +64) -> k16 [kg*48, +48)
    const int o0 = nt * 32;
    const int f0 = kg * 64;

    {
        const int o_l = t >> 3;               // 0..31
        const int tr  = t & 7;                // 8 threads per row
        const float* swr = sw + (size_t)(o0 + o_l) * SW_ROW + (size_t)f0 * 11;
        #pragma unroll
        for (int i = 0; i < 22; ++i) {
            int p4 = tr + i * 8;              // float4 idx 0..175
            float4 v = ((const float4*)swr)[p4];
            uint pos = (uint)p4 * 4;
            #pragma unroll
            for (int c = 0; c < 4; ++c) {
                uint pc = pos + c;            // 0..703
                uint fl = pc / 11u;
                uint j  = pc - fl * 11u;
                float val = (c == 0) ? v.x : (c == 1) ? v.y : (c == 2) ? v.z : v.w;
                kcol[o_l * KC_PAD + fl * NSLOT + j] = f2bf(val);
            }
        }
        #pragma unroll
        for (int i = 0; i < 8; ++i) {
            int fl = tr + i * 8;              // 0..63
            kcol[o_l * KC_PAD + fl * NSLOT + 11] =
                f2bf(bw[(size_t)(o0 + o_l) * IN_F + f0 + fl]);
        }
    }
    __syncthreads();

    {
        const int ol = t & 31;
        const int ph = t >> 5;                // 0..7
        #pragma unroll
        for (int i = 0; i < 12; ++i) {
            int idx  = ph + i * 8;            // 0..95
            int k16l = idx >> 1;
            int half = idx & 1;
            uint4 val = *(const uint4*)&kcol[ol * KC_PAD + k16l * 16 + half * 8];
            ((uint4*)g_Wb)[((size_t)nt * K16S + kg * 48 + k16l) * 64 + half * 32 + ol] = val;
        }
    }
}

// ---- x transpose: x (8192x512) -> g_xT (512x8192), 64x64 LDS tiles ---------
__global__ __launch_bounds__(256) void transpose_x(const float* __restrict__ x) {
    __shared__ float tile[64][65];
    const int t  = threadIdx.x;
    const int rt = blockIdx.x >> 3;           // 0..127 (row tile)
    const int ct = blockIdx.x & 7;            // 0..7   (col tile)
    const int r0 = rt * 64, c0 = ct * 64;

    const int tr  = t >> 4;                   // 0..15
    const int tc4 = (t & 15) * 4;             // 0..60
    #pragma unroll
    for (int j = 0; j < 4; ++j) {
        float4 v = *(const float4*)&x[(size_t)(r0 + tr + 16 * j) * IN_F + c0 + tc4];
        tile[tr + 16 * j][tc4 + 0] = v.x;
        tile[tr + 16 * j][tc4 + 1] = v.y;
        tile[tr + 16 * j][tc4 + 2] = v.z;
        tile[tr + 16 * j][tc4 + 3] = v.w;
    }
    __syncthreads();
    const int rl = t & 63;                    // output row offset (coalesced)
    const int ch = t >> 6;                    // 0..3
    #pragma unroll
    for (int j = 0; j < 16; ++j) {
        int cl = j * 4 + ch;                  // 0..63
        g_xT[(size_t)(c0 + cl) * NROWS + r0 + rl] = tile[rl][cl];
    }
}

// ---- basis eval + select-pack: 3 uint2 (24 B) for one x into LDS row -------
__device__ __forceinline__ void stage_one(float xx, ushort* rowp) {
    float wpos = (xx + 1.0f) * 7.0f;
    float fi = floorf(wpos);
    int   i  = (int)fi;
    float u  = wpos - fi;
    bool inr = (xx >= -1.0f) && (xx < 1.0f);
    int   q  = i - 3;
    float um = 1.0f - u;
    float uu = u * u, u3 = uu * u;
    const float C6 = 1.0f / 6.0f;
    float s0 = (inr && q >= 0) ? C6 : 0.0f;
    float s1 = (inr && q >= -1 && q <= 9) ? C6 : 0.0f;
    float s2 = (inr && q >= -2 && q <= 8) ? C6 : 0.0f;
    float s3 = (inr && q <= 7) ? C6 : 0.0f;
    uint b0 = f2bf(um * um * um * s0);
    uint b1 = f2bf((3.0f * u3 - 6.0f * uu + 4.0f) * s1);
    uint b2 = f2bf((-3.0f * u3 + 3.0f * uu + 3.0f * u + 1.0f) * s2);
    uint b3 = f2bf(u3 * s3);
    int r  = q & 1;
    int e0 = q & ~1;
    uint P0 = r ? (b0 << 16)        : (b0 | (b1 << 16));
    uint P1 = r ? (b1 | (b2 << 16)) : (b2 | (b3 << 16));
    uint P2 = r ? b3                : 0u;
    uint p[6];
    #pragma unroll
    for (int pi = 0; pi < 6; ++pi) {
        int d = 2 * pi - e0;
        p[pi] = (d == 0) ? P0 : (d == 2) ? P1 : (d == 4) ? P2 : 0u;
    }
    p[5] = (p[5] & 0xFFFFu) | ((uint)f2bf(xx) << 16);   // slot 11 = raw x
    uint2 w0; w0.x = p[0]; w0.y = p[1];
    uint2 w1; w1.x = p[2]; w1.y = p[3];
    uint2 w2; w2.x = p[4]; w2.y = p[5];
    *(uint2*)&rowp[0] = w0;
    *(uint2*)&rowp[4] = w1;
    *(uint2*)&rowp[8] = w2;
}

// ---- fused GEMM: wave-private LDS staging, NO barriers, full K per wave ----
// wave tile 32x64; block = 4 waves stacked in M (128 rows x 64 cols)
// grid 512: bx = mb*8 + ng  ->  XCD = ng (B slice 0.79 MB, L2-resident)
__global__ __launch_bounds__(256, 2) void kan_gemm(float* __restrict__ out) {
    __shared__ __align__(16) ushort As[2][4 * 32 * AROW];   // 2 x 14336 B

    const int t    = threadIdx.x;
    const int lane = t & 63;
    const int wv   = t >> 6;          // 0..3
    const int rl   = lane & 31;       // wave-local row
    const int fh   = lane >> 5;       // feature half

    const int bx = blockIdx.x;
    const int ng = bx & 7;            // colgroup -> XCD
    const int mb = bx >> 3;           // 0..63
    const int rowg = mb * 128 + wv * 32 + rl;

    const float* xTr = g_xT + rowg;   // + f*NROWS
    ushort* const stg0 = &As[0][(wv * 32 + rl) * AROW];
    ushort* const stg1 = &As[1][(wv * 32 + rl) * AROW];
    const uint4* Bp = (const uint4*)g_Wb + ((size_t)(ng * 2) * K16S) * 64 + lane;

    f32x16 acc[2] = {};

    // prologue: loads for group 0
    float xa = xTr[(size_t)fh * NROWS];
    float xb = xTr[(size_t)(2 + fh) * NROWS];
    uint4 breg[3][2];
    #pragma unroll
    for (int ks = 0; ks < 3; ++ks) {
        breg[ks][0] = Bp[(size_t)ks * 64];
        breg[ks][1] = Bp[((size_t)K16S + ks) * 64];
    }

    #pragma unroll 1
    for (int g = 0; g < NGROUP; ++g) {
        // -- prefetch group g+1 (x + B), clamped at tail
        const int gn = (g + 1 < NGROUP) ? g + 1 : g;
        float xa_n = xTr[(size_t)(gn * 4 + fh) * NROWS];
        float xb_n = xTr[(size_t)(gn * 4 + 2 + fh) * NROWS];
        uint4 bn[3][2];
        #pragma unroll
        for (int ks = 0; ks < 3; ++ks) {
            bn[ks][0] = Bp[((size_t)(gn * 3 + ks)) * 64];
            bn[ks][1] = Bp[((size_t)K16S + gn * 3 + ks) * 64];
        }

        // -- stage group g into this wave's private slice (buffer g&1)
        ushort* stg = (g & 1) ? stg1 : stg0;
        stage_one(xa, stg + fh * 12);          // feat fh   of this group
        stage_one(xb, stg + fh * 12 + 24);     // feat fh+2

        // -- A-frag reads (intra-wave lgkmcnt only) + MFMA
        #pragma unroll
        for (int ks = 0; ks < 3; ++ks) {
            uint4 av = *(const uint4*)&stg[ks * 16 + fh * 8];
            bf16x8 af = __builtin_bit_cast(bf16x8, av);
            acc[0] = __builtin_amdgcn_mfma_f32_32x32x16_bf16(
                af, __builtin_bit_cast(bf16x8, breg[ks][0]), acc[0], 0, 0, 0);
            acc[1] = __builtin_amdgcn_mfma_f32_32x32x16_bf16(
                af, __builtin_bit_cast(bf16x8, breg[ks][1]), acc[1], 0, 0, 0);
        }

        xa = xa_n; xb = xb_n;
        #pragma unroll
        for (int ks = 0; ks < 3; ++ks) {
            breg[ks][0] = bn[ks][0];
            breg[ks][1] = bn[ks][1];
        }
    }

    // -- epilogue: C layout col=lane&31, row=(reg&3)+8*(reg>>2)+4*(lane>>5)
    #pragma unroll
    for (int nt = 0; nt < 2; ++nt) {
        const int cc = ng * 64 + nt * 32 + rl;
        const int rb = mb * 128 + wv * 32 + 4 * fh;
        #pragma unroll
        for (int reg = 0; reg < 16; ++reg) {
            int rr = rb + (reg & 3) + 8 * (reg >> 2);
            out[(size_t)rr * OUT_F + cc] = acc[nt][reg];
        }
    }
}

extern "C" void kernel_launch(void* const* d_in, const int* in_sizes, int n_in,
                              void* d_out, int out_size, void* d_ws, size_t ws_size,
                              hipStream_t stream) {
    const float* x  = (const float*)d_in[0];
    const float* bw = (const float*)d_in[1];
    const float* sw = (const float*)d_in[2];
    float* out = (float*)d_out;
    hipLaunchKernelGGL(prep_weights, dim3(128), dim3(256), 0, stream, bw, sw);
    hipLaunchKernelGGL(transpose_x, dim3(1024), dim3(256), 0, stream, x);
    hipLaunchKernelGGL(kan_gemm, dim3(512), dim3(256), 0, stream, out);
}

// Round 7
// 170.777 us; speedup vs baseline: 1.2875x; 1.2159x over previous
//
#include <hip/hip_runtime.h>
#include <stdint.h>

#define IN_F 512
#define OUT_F 512
#define NROWS 8192
#define NSLOT 12                 // 11 spline slots + 1 base(x) slot per in-feature
#define KTOT (IN_F * NSLOT)      // 6144
#define K16S (KTOT / 16)         // 384 k16-steps
#define SW_ROW (IN_F * 11)       // 5632 floats per output row of spline_weight
#define KC_PAD 776               // prep kcol row stride (ushorts)
#define AROW 120                 // A-tile row stride (ushorts): 60 words, ~conflict-free b128
#define NGRP 32                  // groups per K-piece (8 feats = 96 kslots each)

typedef __bf16 bf16x8 __attribute__((ext_vector_type(8)));
typedef __bf16 bf16x2 __attribute__((ext_vector_type(2)));
typedef float f32x16 __attribute__((ext_vector_type(16)));

// frag-linear B: uint4 index (ntg*384 + k16)*64 + lane -> 8 bf16 =
//   B[k16*16+(lane>>5)*8+j][ntg*32 + (lane&31)],  k = f*12 + j_slot
__device__ ushort g_Wb[(K16S * 16 + 1) * 512];   // 6.3 MB

__device__ __forceinline__ ushort f2bf(float f) {
    uint32_t u = __builtin_bit_cast(uint32_t, f);
    u += 0x7FFFu + ((u >> 16) & 1u);          // RNE
    return (ushort)(u >> 16);
}

// ---- weight prep: 256 blocks (16 nt x 8 kg x 2 row-half), coalesced --------
__global__ __launch_bounds__(256) void prep_weights(const float* __restrict__ bw,
                                                    const float* __restrict__ sw) {
    __shared__ __align__(16) ushort kcol[16 * KC_PAD];    // 24.8 KB
    const int t  = threadIdx.x;
    const int nt = blockIdx.x & 15;           // 32-out tile
    const int kg = (blockIdx.x >> 4) & 7;     // 64-feat group -> k16 [kg*48,+48)
    const int hv = blockIdx.x >> 7;           // out half (16 outs)
    const int o0 = nt * 32 + hv * 16;
    const int f0 = kg * 64;

    // phase 1: sw slices -> bf16 k-columns in LDS (16 rows x 704 floats)
    {
        const int o_l = t >> 4;               // 0..15
        const int tr  = t & 15;               // 16 threads per row
        const float* swr = sw + (size_t)(o0 + o_l) * SW_ROW + (size_t)f0 * 11;
        #pragma unroll
        for (int i = 0; i < 11; ++i) {
            int p4 = tr + i * 16;             // float4 idx 0..175
            float4 v = ((const float4*)swr)[p4];
            uint pos = (uint)p4 * 4;
            #pragma unroll
            for (int c = 0; c < 4; ++c) {
                uint pc = pos + c;            // 0..703
                uint fl = pc / 11u;
                uint j  = pc - fl * 11u;
                float val = (c == 0) ? v.x : (c == 1) ? v.y : (c == 2) ? v.z : v.w;
                kcol[o_l * KC_PAD + fl * NSLOT + j] = f2bf(val);
            }
        }
        #pragma unroll
        for (int i = 0; i < 4; ++i) {
            int fl = tr * 4 + i;              // 0..63
            kcol[o_l * KC_PAD + fl * NSLOT + 11] =
                f2bf(bw[(size_t)(o0 + o_l) * IN_F + f0 + fl]);
        }
    }
    __syncthreads();

    // phase 2: frag-linear 16B stores (16-lane, 256B bursts)
    {
        const int ol16 = t & 15;
        const int ch   = t >> 4;              // 0..15
        #pragma unroll
        for (int i = 0; i < 6; ++i) {
            int idx  = ch + i * 16;           // 0..95
            int k16l = idx >> 1;
            int hf   = idx & 1;
            uint4 val = *(const uint4*)&kcol[ol16 * KC_PAD + k16l * 16 + hf * 8];
            ((uint4*)g_Wb)[((size_t)nt * K16S + kg * 48 + k16l) * 64 + hf * 32 + hv * 16 + ol16] = val;
        }
    }
}

// ---- basis eval: 12 bf16 slots packed into p[0..5] -------------------------
__device__ __forceinline__ void eval12(float xx, uint p[6]) {
    float wpos = (xx + 1.0f) * 7.0f;
    float fi = floorf(wpos);
    int   i  = (int)fi;
    float u  = wpos - fi;
    bool inr = (xx >= -1.0f) && (xx < 1.0f);
    int   q  = i - 3;
    float um = 1.0f - u;
    float uu = u * u, u3 = uu * u;
    const float C6 = 1.0f / 6.0f;
    float s0 = (inr && q >= 0) ? C6 : 0.0f;
    float s1 = (inr && q >= -1 && q <= 9) ? C6 : 0.0f;
    float s2 = (inr && q >= -2 && q <= 8) ? C6 : 0.0f;
    float s3 = (inr && q <= 7) ? C6 : 0.0f;
    float b0 = um * um * um * s0;
    float b1 = fmaf(3.0f, u3, fmaf(-6.0f, uu, 4.0f)) * s1;
    float b2 = fmaf(-3.0f, u3, fmaf(3.0f, uu, fmaf(3.0f, u, 1.0f))) * s2;
    float b3 = u3 * s3;
    bf16x2 k01; k01[0] = (__bf16)b0; k01[1] = (__bf16)b1;
    bf16x2 k23; k23[0] = (__bf16)b2; k23[1] = (__bf16)b3;
    uint K01 = __builtin_bit_cast(uint, k01);
    uint K23 = __builtin_bit_cast(uint, k23);
    int r  = q & 1;
    int e0 = q & ~1;
    uint P0 = r ? (K01 << 16) : K01;
    uint P1 = r ? ((K01 >> 16) | (K23 << 16)) : K23;
    uint P2 = r ? (K23 >> 16) : 0u;
    #pragma unroll
    for (int pi = 0; pi < 6; ++pi) {
        int d = 2 * pi - e0;
        p[pi] = (d == 0) ? P0 : (d == 2) ? P1 : (d == 4) ? P2 : 0u;
    }
    p[5] = (p[5] & 0xFFFFu) | ((uint)f2bf(xx) << 16);   // slot 11 = raw x
}

// stage 4 features (one float4 of x) -> 96 B = 6 x b128 into LDS
__device__ __forceinline__ void stage4(float4 xv, ushort* dst) {
    uint p[4][6];
    eval12(xv.x, p[0]);
    eval12(xv.y, p[1]);
    eval12(xv.z, p[2]);
    eval12(xv.w, p[3]);
    uint4* d4 = (uint4*)dst;                  // 16B-aligned (row 240B, fq 96B)
    d4[0] = make_uint4(p[0][0], p[0][1], p[0][2], p[0][3]);
    d4[1] = make_uint4(p[0][4], p[0][5], p[1][0], p[1][1]);
    d4[2] = make_uint4(p[1][2], p[1][3], p[1][4], p[1][5]);
    d4[3] = make_uint4(p[2][0], p[2][1], p[2][2], p[2][3]);
    d4[4] = make_uint4(p[2][4], p[2][5], p[3][0], p[3][1]);
    d4[5] = make_uint4(p[3][2], p[3][3], p[3][4], p[3][5]);
}

// ---- fused GEMM: block 128x128, shared A-tile (dbuf, 1 barrier/group) ------
// grid 512: bx = mb*8 + cg*2 + kp; 2 blocks/CU co-resident.
__global__ __launch_bounds__(256, 2) void kan_gemm(const float* __restrict__ x,
                                                   float* __restrict__ out) {
    __shared__ __align__(16) ushort As[2][128 * AROW];   // 2 x 30720 B

    const int t    = threadIdx.x;
    const int lane = t & 63;
    const int wv   = t >> 6;          // 0..3
    const int wr   = wv >> 1;         // wave M half
    const int wc   = wv & 1;          // wave N half
    const int ln31 = lane & 31;
    const int half = lane >> 5;

    const int bx = blockIdx.x;
    const int mb = bx >> 3;           // 0..63
    const int cg = (bx >> 1) & 3;     // 128-col group
    const int kp = bx & 1;            // K half (256 feats)
    const int row_base = mb * 128;

    // staging: thread -> (row, 4 feats)
    const int srow = t >> 1;
    const int fq   = t & 1;
    const float* xp = x + (size_t)(row_base + srow) * IN_F + kp * 256 + fq * 4;
    ushort* const sb0 = &As[0][srow * AROW + fq * 48];
    ushort* const sb1 = &As[1][srow * AROW + fq * 48];

    // B pointers (frag-linear; k16 consecutive per ntg)
    const int ntg0 = cg * 4 + wc * 2;
    const uint4* Bp0 = (const uint4*)g_Wb + ((size_t)ntg0 * K16S + kp * 192) * 64 + lane;
    const uint4* Bp1 = Bp0 + (size_t)K16S * 64;

    f32x16 acc[2][2] = {};

    // prologue: stage group 0, prefetch x(1)
    float4 xv = *(const float4*)xp;
    stage4(xv, sb0);
    float4 xn = *(const float4*)(xp + 8);
    __syncthreads();

    #pragma unroll 1
    for (int g = 0; g < NGRP; ++g) {
        const int cur = g & 1;
        // B frags for this group
        uint4 breg[6][2];
        #pragma unroll
        for (int ks = 0; ks < 6; ++ks) {
            breg[ks][0] = Bp0[(size_t)(g * 6 + ks) * 64];
            breg[ks][1] = Bp1[(size_t)(g * 6 + ks) * 64];
        }
        // x prefetch for g+2 (clamped)
        const int gf = (g + 2 < NGRP) ? g + 2 : (NGRP - 1);
        float4 xf = *(const float4*)(xp + gf * 8);

        // stage group g+1 into the other buffer
        if (g + 1 < NGRP) stage4(xn, cur ? sb0 : sb1);

        // MFMA from As[cur]
        const ushort* Ac = As[cur];
        #pragma unroll
        for (int ks = 0; ks < 6; ++ks) {
            uint4 a0 = *(const uint4*)&Ac[(wr * 64 + ln31) * AROW + ks * 16 + half * 8];
            uint4 a1 = *(const uint4*)&Ac[(wr * 64 + 32 + ln31) * AROW + ks * 16 + half * 8];
            bf16x8 af0 = __builtin_bit_cast(bf16x8, a0);
            bf16x8 af1 = __builtin_bit_cast(bf16x8, a1);
            bf16x8 bf0 = __builtin_bit_cast(bf16x8, breg[ks][0]);
            bf16x8 bf1 = __builtin_bit_cast(bf16x8, breg[ks][1]);
            acc[0][0] = __builtin_amdgcn_mfma_f32_32x32x16_bf16(af0, bf0, acc[0][0], 0, 0, 0);
            acc[0][1] = __builtin_amdgcn_mfma_f32_32x32x16_bf16(af0, bf1, acc[0][1], 0, 0, 0);
            acc[1][0] = __builtin_amdgcn_mfma_f32_32x32x16_bf16(af1, bf0, acc[1][0], 0, 0, 0);
            acc[1][1] = __builtin_amdgcn_mfma_f32_32x32x16_bf16(af1, bf1, acc[1][1], 0, 0, 0);
        }

        xn = xf;
        __syncthreads();   // publish staged buffer; guards reuse next iteration
    }

    // epilogue: C layout col=lane&31, row=(reg&3)+8*(reg>>2)+4*(lane>>5)
    #pragma unroll
    for (int mt = 0; mt < 2; ++mt) {
        #pragma unroll
        for (int nt = 0; nt < 2; ++nt) {
            int rb = row_base + wr * 64 + mt * 32 + 4 * half;
            int cc = cg * 128 + wc * 64 + nt * 32 + ln31;
            #pragma unroll
            for (int reg = 0; reg < 16; ++reg) {
                int rr = rb + (reg & 3) + 8 * (reg >> 2);
                unsafeAtomicAdd(&out[(size_t)rr * OUT_F + cc], acc[mt][nt][reg]);
            }
        }
    }
}

extern "C" void kernel_launch(void* const* d_in, const int* in_sizes, int n_in,
                              void* d_out, int out_size, void* d_ws, size_t ws_size,
                              hipStream_t stream) {
    const float* x  = (const float*)d_in[0];
    const float* bw = (const float*)d_in[1];
    const float* sw = (const float*)d_in[2];
    float* out = (float*)d_out;
    hipMemsetAsync(out, 0, (size_t)out_size * sizeof(float), stream);
    hipLaunchKernelGGL(prep_weights, dim3(256), dim3(256), 0, stream, bw, sw);
    hipLaunchKernelGGL(kan_gemm, dim3(512), dim3(256), 0, stream, x, out);
}

// Round 9
// 165.930 us; speedup vs baseline: 1.3251x; 1.0292x over previous
//
#include <hip/hip_runtime.h>
#include <stdint.h>

#define IN_F 512
#define OUT_F 512
#define NROWS 8192
#define NSLOT 12                 // 11 spline slots + 1 base(x) slot per in-feature
#define KTOT (IN_F * NSLOT)      // 6144
#define K16S (KTOT / 16)         // 384 k16-steps
#define SW_ROW (IN_F * 11)       // 5632 floats per output row of spline_weight
#define KC_PAD 776               // prep kcol row stride (ushorts)
#define AROW 120                 // A-tile row stride (ushorts): 96 slots + pad

typedef __bf16 bf16x8 __attribute__((ext_vector_type(8)));
typedef __bf16 bf16x2 __attribute__((ext_vector_type(2)));
typedef float f32x16 __attribute__((ext_vector_type(16)));

// frag-linear B: uint4 index (ntg*384 + k16)*64 + lane -> 8 bf16 =
//   B[k16*16+(lane>>5)*8+j][ntg*32 + (lane&31)],  k = f*12 + j_slot
__device__ ushort g_Wb[(K16S * 16 + 1) * 512];   // 6.3 MB

__device__ __forceinline__ ushort f2bf(float f) {
    uint32_t u = __builtin_bit_cast(uint32_t, f);
    u += 0x7FFFu + ((u >> 16) & 1u);          // RNE
    return (ushort)(u >> 16);
}

// ---- prep: weights -> frag-linear g_Wb, AND zero d_out (one dispatch) ------
__global__ __launch_bounds__(256) void prep_weights(const float* __restrict__ bw,
                                                    const float* __restrict__ sw,
                                                    float* __restrict__ out) {
    __shared__ __align__(16) ushort kcol[16 * KC_PAD];    // 24.8 KB
    const int t  = threadIdx.x;
    const int b  = blockIdx.x;
    const int nt = b & 15;                    // 32-out tile
    const int kg = (b >> 4) & 7;              // 64-feat group -> k16 [kg*48,+48)
    const int hv = b >> 7;                    // out half (16 outs)
    const int o0 = nt * 32 + hv * 16;
    const int f0 = kg * 64;

    // zero this block's slice of d_out (4096 float4 per block, coalesced)
    {
        float4* o4 = (float4*)out;
        const float4 z = make_float4(0.f, 0.f, 0.f, 0.f);
        #pragma unroll
        for (int i = 0; i < 16; ++i) o4[(size_t)b * 4096 + i * 256 + t] = z;
    }

    // phase 1: sw slices -> bf16 k-columns in LDS (16 rows x 704 floats)
    {
        const int o_l = t >> 4;               // 0..15
        const int tr  = t & 15;               // 16 threads per row
        const float* swr = sw + (size_t)(o0 + o_l) * SW_ROW + (size_t)f0 * 11;
        #pragma unroll
        for (int i = 0; i < 11; ++i) {
            int p4 = tr + i * 16;             // float4 idx 0..175
            float4 v = ((const float4*)swr)[p4];
            uint pos = (uint)p4 * 4;
            #pragma unroll
            for (int c = 0; c < 4; ++c) {
                uint pc = pos + c;            // 0..703
                uint fl = pc / 11u;
                uint j  = pc - fl * 11u;
                float val = (c == 0) ? v.x : (c == 1) ? v.y : (c == 2) ? v.z : v.w;
                kcol[o_l * KC_PAD + fl * NSLOT + j] = f2bf(val);
            }
        }
        #pragma unroll
        for (int i = 0; i < 4; ++i) {
            int fl = tr * 4 + i;              // 0..63
            kcol[o_l * KC_PAD + fl * NSLOT + 11] =
                f2bf(bw[(size_t)(o0 + o_l) * IN_F + f0 + fl]);
        }
    }
    __syncthreads();

    // phase 2: frag-linear 16B stores (16-lane, 256B bursts)
    {
        const int ol16 = t & 15;
        const int ch   = t >> 4;              // 0..15
        #pragma unroll
        for (int i = 0; i < 6; ++i) {
            int idx  = ch + i * 16;           // 0..95
            int k16l = idx >> 1;
            int hf   = idx & 1;
            uint4 val = *(const uint4*)&kcol[ol16 * KC_PAD + k16l * 16 + hf * 8];
            ((uint4*)g_Wb)[((size_t)nt * K16S + kg * 48 + k16l) * 64 + hf * 32 + hv * 16 + ol16] = val;
        }
    }
}

// ---- basis eval: 12 bf16 slots packed into p[0..5] -------------------------
__device__ __forceinline__ void eval12(float xx, uint p[6]) {
    float wpos = (xx + 1.0f) * 7.0f;
    float fi = floorf(wpos);
    int   i  = (int)fi;
    float u  = wpos - fi;
    bool inr = (xx >= -1.0f) && (xx < 1.0f);
    int   q  = i - 3;
    float um = 1.0f - u;
    float uu = u * u, u3 = uu * u;
    const float C6 = 1.0f / 6.0f;
    float s0 = (inr && q >= 0) ? C6 : 0.0f;
    float s1 = (inr && q >= -1 && q <= 9) ? C6 : 0.0f;
    float s2 = (inr && q >= -2 && q <= 8) ? C6 : 0.0f;
    float s3 = (inr && q <= 7) ? C6 : 0.0f;
    float b0 = um * um * um * s0;
    float b1 = fmaf(3.0f, u3, fmaf(-6.0f, uu, 4.0f)) * s1;
    float b2 = fmaf(-3.0f, u3, fmaf(3.0f, uu, fmaf(3.0f, u, 1.0f))) * s2;
    float b3 = u3 * s3;
    bf16x2 k01; k01[0] = (__bf16)b0; k01[1] = (__bf16)b1;
    bf16x2 k23; k23[0] = (__bf16)b2; k23[1] = (__bf16)b3;
    uint K01 = __builtin_bit_cast(uint, k01);
    uint K23 = __builtin_bit_cast(uint, k23);
    int r  = q & 1;
    int e0 = q & ~1;
    uint P0 = r ? (K01 << 16) : K01;
    uint P1 = r ? ((K01 >> 16) | (K23 << 16)) : K23;
    uint P2 = r ? (K23 >> 16) : 0u;
    #pragma unroll
    for (int pi = 0; pi < 6; ++pi) {
        int d = 2 * pi - e0;
        p[pi] = (d == 0) ? P0 : (d == 2) ? P1 : (d == 4) ? P2 : 0u;
    }
    p[5] = (p[5] & 0xFFFFu) | ((uint)f2bf(xx) << 16);   // slot 11 = raw x
}

// stage 4 features -> 96 B via 12x ds_write_b64 (low-conflict pattern)
__device__ __forceinline__ void stage4(float4 xv, ushort* dst) {
    uint p[4][6];
    eval12(xv.x, p[0]);
    eval12(xv.y, p[1]);
    eval12(xv.z, p[2]);
    eval12(xv.w, p[3]);
    #pragma unroll
    for (int c = 0; c < 4; ++c) {
        uint2 w0; w0.x = p[c][0]; w0.y = p[c][1];
        uint2 w1; w1.x = p[c][2]; w1.y = p[c][3];
        uint2 w2; w2.x = p[c][4]; w2.y = p[c][5];
        *(uint2*)&dst[c * 12 + 0] = w0;
        *(uint2*)&dst[c * 12 + 4] = w1;
        *(uint2*)&dst[c * 12 + 8] = w2;
    }
}

// ---- fused GEMM: block 128x128, single-buffer A, 3 blocks/CU ---------------
// grid 1024: bx = mb*16 + cg*4 + kp  ->  XCD = (cg*4+kp)%8: 2 cg/XCD (B 3.1MB, L2-fit)
__global__ __launch_bounds__(256, 3) void kan_gemm(const float* __restrict__ x,
                                                   float* __restrict__ out) {
    __shared__ __align__(16) ushort As[128 * AROW];   // 30720 B

    const int t    = threadIdx.x;
    const int lane = t & 63;
    const int wv   = t >> 6;          // 0..3
    const int wr   = wv >> 1;         // wave M half
    const int wc   = wv & 1;          // wave N half
    const int ln31 = lane & 31;
    const int half = lane >> 5;

    const int bx = blockIdx.x;
    const int mb = bx >> 4;           // 0..63
    const int cg = (bx >> 2) & 3;     // 128-col group
    const int kp = bx & 3;            // K quarter (128 feats, 16 groups)
    const int row_base = mb * 128;

    // staging: thread -> (row, 4 feats)
    const int srow = t >> 1;
    const int fq   = t & 1;
    const float* xp = x + (size_t)(row_base + srow) * IN_F + kp * 128 + fq * 4;
    ushort* const sb = &As[srow * AROW + fq * 48];

    const int ntg0 = cg * 4 + wc * 2;
    const uint4* Bp0 = (const uint4*)g_Wb + (size_t)ntg0 * K16S * 64 + lane;
    const uint4* Bp1 = Bp0 + (size_t)K16S * 64;

    f32x16 acc[2][2] = {};

    float4 xv = *(const float4*)xp;   // group 0 of this K-quarter

    #pragma unroll 1
    for (int gi = 0; gi < 16; ++gi) {
        const int g = kp * 16 + gi;   // global 8-feat group 0..63
        // B frags for this group
        uint4 breg[6][2];
        #pragma unroll
        for (int ks = 0; ks < 6; ++ks) {
            breg[ks][0] = Bp0[(size_t)(g * 6 + ks) * 64];
            breg[ks][1] = Bp1[(size_t)(g * 6 + ks) * 64];
        }
        // x prefetch for next group (clamped)
        const int gn = (gi + 1 < 16) ? gi + 1 : gi;
        float4 xn = *(const float4*)(xp + gn * 8);

        __syncthreads();              // prior iteration's A-frag reads done
        stage4(xv, sb);
        __syncthreads();              // publish A-tile

        #pragma unroll
        for (int ks = 0; ks < 6; ++ks) {
            uint4 a0 = *(const uint4*)&As[(wr * 64 + ln31) * AROW + ks * 16 + half * 8];
            uint4 a1 = *(const uint4*)&As[(wr * 64 + 32 + ln31) * AROW + ks * 16 + half * 8];
            bf16x8 af0 = __builtin_bit_cast(bf16x8, a0);
            bf16x8 af1 = __builtin_bit_cast(bf16x8, a1);
            bf16x8 bf0 = __builtin_bit_cast(bf16x8, breg[ks][0]);
            bf16x8 bf1 = __builtin_bit_cast(bf16x8, breg[ks][1]);
            acc[0][0] = __builtin_amdgcn_mfma_f32_32x32x16_bf16(af0, bf0, acc[0][0], 0, 0, 0);
            acc[0][1] = __builtin_amdgcn_mfma_f32_32x32x16_bf16(af0, bf1, acc[0][1], 0, 0, 0);
            acc[1][0] = __builtin_amdgcn_mfma_f32_32x32x16_bf16(af1, bf0, acc[1][0], 0, 0, 0);
            acc[1][1] = __builtin_amdgcn_mfma_f32_32x32x16_bf16(af1, bf1, acc[1][1], 0, 0, 0);
        }
        xv = xn;
    }

    // epilogue: C layout col=lane&31, row=(reg&3)+8*(reg>>2)+4*(lane>>5)
    #pragma unroll
    for (int mt = 0; mt < 2; ++mt) {
        #pragma unroll
        for (int nt2 = 0; nt2 < 2; ++nt2) {
            int rb = row_base + wr * 64 + mt * 32 + 4 * half;
            int cc = cg * 128 + wc * 64 + nt2 * 32 + ln31;
            #pragma unroll
            for (int reg = 0; reg < 16; ++reg) {
                int rr = rb + (reg & 3) + 8 * (reg >> 2);
                unsafeAtomicAdd(&out[(size_t)rr * OUT_F + cc], acc[mt][nt2][reg]);
            }
        }
    }
}

extern "C" void kernel_launch(void* const* d_in, const int* in_sizes, int n_in,
                              void* d_out, int out_size, void* d_ws, size_t ws_size,
                              hipStream_t stream) {
    const float* x  = (const float*)d_in[0];
    const float* bw = (const float*)d_in[1];
    const float* sw = (const float*)d_in[2];
    float* out = (float*)d_out;
    hipLaunchKernelGGL(prep_weights, dim3(256), dim3(256), 0, stream, bw, sw, out);
    hipLaunchKernelGGL(kan_gemm, dim3(1024), dim3(256), 0, stream, x, out);
}